// Round 2
// baseline (926.328 us; speedup 1.0000x reference)
//
#include <hip/hip_runtime.h>
#include <hip/hip_bf16.h>
#include <stdint.h>

// MLA attention, bf16 MFMA pipeline.
// B=2 S=2048 HID=2048 H=16 KV=4 HD=128 RD=64 FULL=192
// RoPE quirk: reference indexes cos/sin by HEAD index (x.shape[-2]), not position.

typedef __bf16 bf16;
typedef __bf16 bf16x8 __attribute__((ext_vector_type(8)));
typedef __bf16 bf16x4 __attribute__((ext_vector_type(4)));
typedef float f32x4 __attribute__((ext_vector_type(4)));

#define GAS __attribute__((address_space(1)))
#define LAS __attribute__((address_space(3)))

__device__ __forceinline__ void gload16(const void* g, void* l) {
  __builtin_amdgcn_global_load_lds((GAS void*)(g), (LAS void*)(l), 16, 0, 0);
}

__device__ __forceinline__ f32x4 mfma16(bf16x8 a, bf16x8 b, f32x4 c) {
  return __builtin_amdgcn_mfma_f32_16x16x32_bf16(a, b, c, 0, 0, 0);
}

// ---------------- workspace layout (bytes) ----------------
#define OFF_XB    0ull                         // X bf16       4096x2048
#define OFF_WQT   (OFF_XB    + 16777216ull)    // WqT          2048x2048
#define OFF_WQRT  (OFF_WQT   + 8388608ull)     // WqropeT      1024x2048
#define OFF_WKVCT (OFF_WQRT  + 4194304ull)     // WkvcT        512x2048
#define OFF_WKDT  (OFF_WKVCT + 2097152ull)     // WkdecT       512x512
#define OFF_WVDT  (OFF_WKDT  + 524288ull)      // WvdecT       512x512
#define OFF_WKRT  (OFF_WVDT  + 524288ull)      // WkropeT      256x512
#define OFF_WOT   (OFF_WKRT  + 262144ull)      // WoT(gather)  2048x2048
#define OFF_CB    (OFF_WOT   + 8388608ull)     // c bf16       4096x512
#define OFF_QBUF  (OFF_CB    + 4194304ull)     // q (b,h,s,192)
#define OFF_KBUF  (OFF_QBUF  + 25165824ull)    // k (b,kv,s,192)
#define OFF_VT    (OFF_KBUF  + 6291456ull)     // vT (b,kv,128,s)
#define OFF_QRR   (OFF_VT    + 4194304ull)     // q-rope raw   4096x1024
#define OFF_KRR   (OFF_QRR   + 8388608ull)     // k-rope raw   4096x256
#define OFF_OBUF  (OFF_KRR   + 2097152ull)     // attn out     4096x2048
// total ~103 MB

// ---------------- cast f32 -> bf16 ----------------
__global__ void cast_x_kernel(const float* __restrict__ in, bf16* __restrict__ out, int n4) {
  int i = blockIdx.x * blockDim.x + threadIdx.x;
  int stride = gridDim.x * blockDim.x;
  for (; i < n4; i += stride) {
    float4 v = reinterpret_cast<const float4*>(in)[i];
    bf16x4 o;
    o[0] = (bf16)v.x; o[1] = (bf16)v.y; o[2] = (bf16)v.z; o[3] = (bf16)v.w;
    reinterpret_cast<bf16x4*>(out)[i] = o;
  }
}

// ---------------- transpose-cast: in (Kd x Nd) f32 -> out (Nd x Kd) bf16 ----------------
// gather=1: input row remapped k -> (k>>7)*192 + (k&127)  (Wo nope-row gather)
__global__ void transpose_cast_kernel(const float* __restrict__ in, bf16* __restrict__ out,
                                      int Kd, int Nd, int gather) {
  __shared__ float t[32][33];
  int n0 = blockIdx.x * 32, k0 = blockIdx.y * 32;
  int tx = threadIdx.x, ty = threadIdx.y;
#pragma unroll
  for (int i = 0; i < 4; i++) {
    int k = k0 + ty + i * 8;
    int kr = gather ? ((k >> 7) * 192 + (k & 127)) : k;
    t[ty + i * 8][tx] = in[(size_t)kr * Nd + n0 + tx];
  }
  __syncthreads();
#pragma unroll
  for (int i = 0; i < 4; i++) {
    int n = n0 + ty + i * 8;
    out[(size_t)n * Kd + k0 + tx] = (bf16)t[tx][ty + i * 8];
  }
}

// ---------------- GEMM: C(MxN) = A(MxK,bf16,rowmaj) @ BT(NxK,bf16,rowmaj)^T ----------------
// 128x128 tile, 4 waves, BK=32, global_load_lds staging with source pre-swizzle.
// MODE 0: bf16 plain rowmajor   1: f32 plain rowmajor
//      2: q-nope scatter (b,h,s,192)[0:128]   3: k-nope scatter (b,kv,s,192)[0:128]
//      4: v transpose scatter (b,kv,128,s)
template<int MODE>
__global__ __launch_bounds__(256, 2)
void gemm_bt(const bf16* __restrict__ A, const bf16* __restrict__ BT,
             void* __restrict__ outp, int M, int N, int K) {
  __shared__ bf16 ldsA[128 * 32];
  __shared__ bf16 ldsB[128 * 32];
  const int tid = threadIdx.x;
  const int wid = tid >> 6, lane = tid & 63;
  const int lr = lane & 15, lg = lane >> 4;
  const int wr = wid >> 1, wc = wid & 1;
  const int m0 = blockIdx.y * 128, n0 = blockIdx.x * 128;

  const int rowA = tid >> 2;                    // 0..63 within a 64-row half
  const int cg = (tid & 3) ^ (rowA & 3);        // pre-swizzled global k-chunk
  const int slot = lg ^ (lane & 3);             // matching LDS read slot

  const f32x4 fzero = {0.f, 0.f, 0.f, 0.f};
  f32x4 acc[4][4];
#pragma unroll
  for (int m = 0; m < 4; m++)
#pragma unroll
    for (int n = 0; n < 4; n++) acc[m][n] = fzero;

  const int nk = K >> 5;
  for (int kt = 0; kt < nk; kt++) {
    const int kb = kt * 32 + cg * 8;
#pragma unroll
    for (int r = 0; r < 2; r++) {
      gload16(&A[(size_t)(m0 + r * 64 + rowA) * K + kb], &ldsA[r * 2048 + wid * 512]);
      gload16(&BT[(size_t)(n0 + r * 64 + rowA) * K + kb], &ldsB[r * 2048 + wid * 512]);
    }
    __syncthreads();
    bf16x8 af[4], bfr[4];
#pragma unroll
    for (int m = 0; m < 4; m++)
      af[m] = *reinterpret_cast<const bf16x8*>(&ldsA[(wr * 64 + m * 16 + lr) * 32 + slot * 8]);
#pragma unroll
    for (int n = 0; n < 4; n++)
      bfr[n] = *reinterpret_cast<const bf16x8*>(&ldsB[(wc * 64 + n * 16 + lr) * 32 + slot * 8]);
#pragma unroll
    for (int m = 0; m < 4; m++)
#pragma unroll
      for (int n = 0; n < 4; n++) acc[m][n] = mfma16(af[m], bfr[n], acc[m][n]);
    __syncthreads();
  }

#pragma unroll
  for (int m = 0; m < 4; m++)
#pragma unroll
    for (int n = 0; n < 4; n++)
#pragma unroll
      for (int i = 0; i < 4; i++) {
        int row = m0 + wr * 64 + m * 16 + 4 * lg + i;
        int col = n0 + wc * 64 + n * 16 + lr;
        float v = acc[m][n][i];
        if (MODE == 0) {
          ((bf16*)outp)[(size_t)row * N + col] = (bf16)v;
        } else if (MODE == 1) {
          ((float*)outp)[(size_t)row * N + col] = v;
        } else if (MODE == 2) {
          int b = row >> 11, s = row & 2047, h = col >> 7, d = col & 127;
          ((bf16*)outp)[((size_t)(b * 16 + h) * 2048 + s) * 192 + d] = (bf16)v;
        } else if (MODE == 3) {
          int b = row >> 11, s = row & 2047, kv = col >> 7, d = col & 127;
          ((bf16*)outp)[((size_t)(b * 4 + kv) * 2048 + s) * 192 + d] = (bf16)v;
        } else if (MODE == 4) {
          int b = row >> 11, s = row & 2047, kv = col >> 7, d = col & 127;
          ((bf16*)outp)[((size_t)(b * 4 + kv) * 128 + d) * 2048 + s] = (bf16)v;
        }
      }
}

// ---------------- RoPE (position = head index, per reference quirk) ----------------
__global__ void rope_q_kernel(const bf16* __restrict__ raw, bf16* __restrict__ qbuf) {
  int idx = blockIdx.x * 256 + threadIdx.x;   // (rs,h,i): 4096*16*32
  int i = idx & 31;
  int h = (idx >> 5) & 15;
  int rs = idx >> 9;
  int b = rs >> 11, s = rs & 2047;
  float x1 = (float)raw[(size_t)rs * 1024 + h * 64 + 2 * i];
  float x2 = (float)raw[(size_t)rs * 1024 + h * 64 + 2 * i + 1];
  float freq = __expf(-(float)(2 * i) * (9.210340371976184f / 64.f)); // 10000^(-2i/64)
  float ang = (float)h * freq;
  float sn, cs;
  __sincosf(ang, &sn, &cs);
  size_t o = ((size_t)(b * 16 + h) * 2048 + s) * 192 + 128 + 2 * i;
  qbuf[o] = (bf16)(x1 * cs - x2 * sn);
  qbuf[o + 1] = (bf16)(x1 * sn + x2 * cs);
}

__global__ void rope_k_kernel(const bf16* __restrict__ raw, bf16* __restrict__ kbuf) {
  int idx = blockIdx.x * 256 + threadIdx.x;   // (rs,kv,i): 4096*4*32
  int i = idx & 31;
  int kv = (idx >> 5) & 3;
  int rs = idx >> 7;
  int b = rs >> 11, s = rs & 2047;
  float x1 = (float)raw[(size_t)rs * 256 + kv * 64 + 2 * i];
  float x2 = (float)raw[(size_t)rs * 256 + kv * 64 + 2 * i + 1];
  float freq = __expf(-(float)(2 * i) * (9.210340371976184f / 64.f));
  float ang = (float)kv * freq;
  float sn, cs;
  __sincosf(ang, &sn, &cs);
  size_t o = ((size_t)(b * 4 + kv) * 2048 + s) * 192 + 128 + 2 * i;
  kbuf[o] = (bf16)(x1 * cs - x2 * sn);
  kbuf[o + 1] = (bf16)(x1 * sn + x2 * cs);
}

// ---------------- flash attention (causal, GQA 4:1) ----------------
// grid (S/64, H, B); 4 waves x 16 q-rows; KV tile 64; K/V direct from global (L2-resident).
__global__ __launch_bounds__(256, 2)
void attn_kernel(const bf16* __restrict__ qbuf, const bf16* __restrict__ kbuf,
                 const bf16* __restrict__ vt, bf16* __restrict__ obuf) {
  const int tid = threadIdx.x;
  const int wid = tid >> 6, lane = tid & 63;
  const int lr = lane & 15, lg = lane >> 4;
  const int bx = blockIdx.x, h = blockIdx.y, b = blockIdx.z;
  const int q0 = bx * 64, qrb = q0 + wid * 16;
  const bf16* Q = qbuf + (size_t)(b * 16 + h) * 2048 * 192;
  const bf16* Kp = kbuf + (size_t)(b * 4 + (h >> 2)) * 2048 * 192;
  const bf16* Vp = vt + (size_t)(b * 4 + (h >> 2)) * 128 * 2048;
  __shared__ __align__(16) bf16 Plds[4][16][72];   // per-wave P tile, padded stride

  bf16x8 qf[6];
#pragma unroll
  for (int kk = 0; kk < 6; kk++)
    qf[kk] = *reinterpret_cast<const bf16x8*>(&Q[(size_t)(qrb + lr) * 192 + kk * 32 + lg * 8]);

  const f32x4 fzero = {0.f, 0.f, 0.f, 0.f};
  f32x4 acco[8];
#pragma unroll
  for (int nn = 0; nn < 8; nn++) acco[nn] = fzero;
  float mrow[4] = {-1e30f, -1e30f, -1e30f, -1e30f};
  float lsum[4] = {0.f, 0.f, 0.f, 0.f};
  const float scale = 0.07216878364870323f;  // 1/sqrt(192)

  const int ntile = bx + 1;
  for (int j = 0; j < ntile; j++) {
    const int k0 = j * 64;
    f32x4 sacc[4];
#pragma unroll
    for (int n = 0; n < 4; n++) sacc[n] = fzero;
#pragma unroll
    for (int n = 0; n < 4; n++) {
#pragma unroll
      for (int kk = 0; kk < 6; kk++) {
        bf16x8 kf = *reinterpret_cast<const bf16x8*>(
            &Kp[(size_t)(k0 + n * 16 + lr) * 192 + kk * 32 + lg * 8]);
        sacc[n] = mfma16(qf[kk], kf, sacc[n]);
      }
    }
#pragma unroll
    for (int i = 0; i < 4; i++) {
      const int row = qrb + 4 * lg + i;
      float s[4];
#pragma unroll
      for (int n = 0; n < 4; n++) {
        s[n] = sacc[n][i] * scale;
        if (k0 + n * 16 + lr > row) s[n] = -1e30f;
      }
      float mx = fmaxf(fmaxf(s[0], s[1]), fmaxf(s[2], s[3]));
#pragma unroll
      for (int off = 1; off < 16; off <<= 1) mx = fmaxf(mx, __shfl_xor(mx, off, 16));
      float mnew = fmaxf(mrow[i], mx);
      float fs = __expf(mrow[i] - mnew);
      float p[4], sum = 0.f;
#pragma unroll
      for (int n = 0; n < 4; n++) { p[n] = __expf(s[n] - mnew); sum += p[n]; }
#pragma unroll
      for (int off = 1; off < 16; off <<= 1) sum += __shfl_xor(sum, off, 16);
      mrow[i] = mnew;
      lsum[i] = lsum[i] * fs + sum;
#pragma unroll
      for (int n = 0; n < 4; n++) Plds[wid][4 * lg + i][n * 16 + lr] = (bf16)p[n];
#pragma unroll
      for (int nn = 0; nn < 8; nn++) acco[nn][i] *= fs;
    }
    // PV: per-wave LDS, same-wave dep — compiler inserts lgkmcnt waits.
#pragma unroll
    for (int ks = 0; ks < 2; ks++) {
      bf16x8 pf = *reinterpret_cast<const bf16x8*>(&Plds[wid][lr][ks * 32 + lg * 8]);
#pragma unroll
      for (int nn = 0; nn < 8; nn++) {
        bf16x8 vf = *reinterpret_cast<const bf16x8*>(
            &Vp[(size_t)(nn * 16 + lr) * 2048 + k0 + ks * 32 + lg * 8]);
        acco[nn] = mfma16(pf, vf, acco[nn]);
      }
    }
  }
#pragma unroll
  for (int nn = 0; nn < 8; nn++)
#pragma unroll
    for (int i = 0; i < 4; i++) {
      int row = qrb + 4 * lg + i;
      float o = acco[nn][i] / lsum[i];
      obuf[(size_t)(b * 2048 + row) * 2048 + h * 128 + nn * 16 + lr] = (bf16)o;
    }
}

// ---------------- launcher ----------------
extern "C" void kernel_launch(void* const* d_in, const int* in_sizes, int n_in,
                              void* d_out, int out_size, void* d_ws, size_t ws_size,
                              hipStream_t stream) {
  (void)in_sizes; (void)n_in; (void)out_size; (void)ws_size;
  const float* Xf     = (const float*)d_in[0];
  const float* Wq     = (const float*)d_in[1];
  const float* Wkvc   = (const float*)d_in[2];
  const float* Wkdec  = (const float*)d_in[3];
  const float* Wvdec  = (const float*)d_in[4];
  const float* Wqrope = (const float*)d_in[5];
  const float* Wkrope = (const float*)d_in[6];
  const float* Wo     = (const float*)d_in[7];
  float* Out = (float*)d_out;
  char* ws = (char*)d_ws;

  bf16* Xb     = (bf16*)(ws + OFF_XB);
  bf16* WqT    = (bf16*)(ws + OFF_WQT);
  bf16* WqrT   = (bf16*)(ws + OFF_WQRT);
  bf16* WkvcT  = (bf16*)(ws + OFF_WKVCT);
  bf16* WkdT   = (bf16*)(ws + OFF_WKDT);
  bf16* WvdT   = (bf16*)(ws + OFF_WVDT);
  bf16* WkrT   = (bf16*)(ws + OFF_WKRT);
  bf16* WoT    = (bf16*)(ws + OFF_WOT);
  bf16* Cb     = (bf16*)(ws + OFF_CB);
  bf16* Qbuf   = (bf16*)(ws + OFF_QBUF);
  bf16* Kbuf   = (bf16*)(ws + OFF_KBUF);
  bf16* Vt     = (bf16*)(ws + OFF_VT);
  bf16* Qrr    = (bf16*)(ws + OFF_QRR);
  bf16* Krr    = (bf16*)(ws + OFF_KRR);
  bf16* Obuf   = (bf16*)(ws + OFF_OBUF);

  dim3 tb(32, 8);
  cast_x_kernel<<<2048, 256, 0, stream>>>(Xf, Xb, (4096 * 2048) / 4);
  transpose_cast_kernel<<<dim3(64, 64), tb, 0, stream>>>(Wq, WqT, 2048, 2048, 0);
  transpose_cast_kernel<<<dim3(32, 64), tb, 0, stream>>>(Wqrope, WqrT, 2048, 1024, 0);
  transpose_cast_kernel<<<dim3(16, 64), tb, 0, stream>>>(Wkvc, WkvcT, 2048, 512, 0);
  transpose_cast_kernel<<<dim3(16, 16), tb, 0, stream>>>(Wkdec, WkdT, 512, 512, 0);
  transpose_cast_kernel<<<dim3(16, 16), tb, 0, stream>>>(Wvdec, WvdT, 512, 512, 0);
  transpose_cast_kernel<<<dim3(8, 16), tb, 0, stream>>>(Wkrope, WkrT, 512, 256, 0);
  transpose_cast_kernel<<<dim3(64, 64), tb, 0, stream>>>(Wo, WoT, 2048, 2048, 1);

  gemm_bt<0><<<dim3(4, 32), 256, 0, stream>>>(Xb, WkvcT, Cb, 4096, 512, 2048);
  gemm_bt<2><<<dim3(16, 32), 256, 0, stream>>>(Xb, WqT, Qbuf, 4096, 2048, 2048);
  gemm_bt<0><<<dim3(8, 32), 256, 0, stream>>>(Xb, WqrT, Qrr, 4096, 1024, 2048);
  gemm_bt<3><<<dim3(4, 32), 256, 0, stream>>>(Cb, WkdT, Kbuf, 4096, 512, 512);
  gemm_bt<4><<<dim3(4, 32), 256, 0, stream>>>(Cb, WvdT, Vt, 4096, 512, 512);
  gemm_bt<0><<<dim3(2, 32), 256, 0, stream>>>(Cb, WkrT, Krr, 4096, 256, 512);

  rope_q_kernel<<<8192, 256, 0, stream>>>(Qrr, Qbuf);
  rope_k_kernel<<<2048, 256, 0, stream>>>(Krr, Kbuf);

  attn_kernel<<<dim3(32, 16, 2), 256, 0, stream>>>(Qbuf, Kbuf, Vt, Obuf);

  gemm_bt<1><<<dim3(16, 32), 256, 0, stream>>>(Obuf, WoT, Out, 4096, 2048, 2048);
}

// Round 3
// 476.455 us; speedup vs baseline: 1.9442x; 1.9442x over previous
//
#include <hip/hip_runtime.h>
#include <hip/hip_bf16.h>
#include <stdint.h>

// MLA attention, bf16 MFMA pipeline.
// B=2 S=2048 HID=2048 H=16 KV=4 HD=128 RD=64 FULL=192
// RoPE quirk: reference indexes cos/sin by HEAD index (x.shape[-2]), not position.

typedef __bf16 bf16;
typedef __bf16 bf16x8 __attribute__((ext_vector_type(8)));
typedef __bf16 bf16x4 __attribute__((ext_vector_type(4)));
typedef float f32x4 __attribute__((ext_vector_type(4)));

#define GAS __attribute__((address_space(1)))
#define LAS __attribute__((address_space(3)))

__device__ __forceinline__ void gload16(const void* g, void* l) {
  __builtin_amdgcn_global_load_lds((GAS void*)(g), (LAS void*)(l), 16, 0, 0);
}

__device__ __forceinline__ f32x4 mfma16(bf16x8 a, bf16x8 b, f32x4 c) {
  return __builtin_amdgcn_mfma_f32_16x16x32_bf16(a, b, c, 0, 0, 0);
}

// ---------------- workspace layout (bytes) ----------------
// NOTE: WQT/WQRT/WKVCT must stay adjacent (mega-GEMM 1 B-operand),
//       WKDT/WVDT/WKRT must stay adjacent (mega-GEMM 2 B-operand).
#define OFF_XB    0ull                         // X bf16       4096x2048
#define OFF_WQT   (OFF_XB    + 16777216ull)    // WqT          2048x2048
#define OFF_WQRT  (OFF_WQT   + 8388608ull)     // WqropeT      1024x2048
#define OFF_WKVCT (OFF_WQRT  + 4194304ull)     // WkvcT        512x2048
#define OFF_WKDT  (OFF_WKVCT + 2097152ull)     // WkdecT       512x512
#define OFF_WVDT  (OFF_WKDT  + 524288ull)      // WvdecT       512x512
#define OFF_WKRT  (OFF_WVDT  + 524288ull)      // WkropeT      256x512
#define OFF_WOT   (OFF_WKRT  + 262144ull)      // WoT(gather)  2048x2048
#define OFF_CB    (OFF_WOT   + 8388608ull)     // c bf16       4096x512
#define OFF_QBUF  (OFF_CB    + 4194304ull)     // q (b,h,s,192)
#define OFF_KBUF  (OFF_QBUF  + 25165824ull)    // k (b,kv,s,192)
#define OFF_VT    (OFF_KBUF  + 6291456ull)     // vT (b,kv,128,s)
#define OFF_QRR   (OFF_VT    + 4194304ull)     // q-rope raw   4096x1024
#define OFF_KRR   (OFF_QRR   + 8388608ull)     // k-rope raw   4096x256
#define OFF_OBUF  (OFF_KRR   + 2097152ull)     // attn out     4096x2048
// total ~103 MB

// ---------------- cast f32 -> bf16 ----------------
__global__ void cast_x_kernel(const float* __restrict__ in, bf16* __restrict__ out, int n4) {
  int i = blockIdx.x * blockDim.x + threadIdx.x;
  int stride = gridDim.x * blockDim.x;
  for (; i < n4; i += stride) {
    float4 v = reinterpret_cast<const float4*>(in)[i];
    bf16x4 o;
    o[0] = (bf16)v.x; o[1] = (bf16)v.y; o[2] = (bf16)v.z; o[3] = (bf16)v.w;
    reinterpret_cast<bf16x4*>(out)[i] = o;
  }
}

// ---------------- fused transpose-cast: 7 matrices, one launch ----------------
// each: in (Kd x Nd) f32 -> out (Nd x Kd) bf16; gather=1 remaps input row
// k -> (k>>7)*192 + (k&127) (Wo nope-row gather).
struct TDescs {
  const float* in[7];
  bf16* out[7];
  int Kd[7], Nd[7], gather[7];
  int tile0[8];
};

__global__ void transpose_cast_fused(TDescs D) {
  __shared__ float t[32][33];
  int bid = blockIdx.x;
  int m = 0;
  while (bid >= D.tile0[m + 1]) m++;        // uniform per block
  int local = bid - D.tile0[m];
  const float* in = D.in[m];
  bf16* out = D.out[m];
  int Kd = D.Kd[m], Nd = D.Nd[m], gather = D.gather[m];
  int txn = Nd >> 5;
  int n0 = (local % txn) * 32, k0 = (local / txn) * 32;
  int tx = threadIdx.x, ty = threadIdx.y;
#pragma unroll
  for (int i = 0; i < 4; i++) {
    int k = k0 + ty + i * 8;
    int kr = gather ? ((k >> 7) * 192 + (k & 127)) : k;
    t[ty + i * 8][tx] = in[(size_t)kr * Nd + n0 + tx];
  }
  __syncthreads();
#pragma unroll
  for (int i = 0; i < 4; i++) {
    int n = n0 + ty + i * 8;
    out[(size_t)n * Kd + k0 + tx] = (bf16)t[tx][ty + i * 8];
  }
}

// ---------------- GEMM: C(MxN) = A(MxK,bf16,rowmaj) @ BT(NxK,bf16,rowmaj)^T ----------------
// 128x128 tile, 4 waves, BK=32, global_load_lds staging with source pre-swizzle.
// MODE 1: f32 plain rowmajor (out0)
// MODE 6: mega1 routing: col<2048 -> Qbuf scatter (out0), col<3072 -> Qrr rowmaj
//         (out1, width 1024), else Cb rowmaj (out2, width 512)
// MODE 7: mega2 routing: col<512 -> Kbuf scatter (out0), col<1024 -> Vt transpose
//         scatter (out1), else Krr rowmaj (out2, width 256)
template<int MODE>
__global__ __launch_bounds__(256, 2)
void gemm_bt(const bf16* __restrict__ A, const bf16* __restrict__ BT,
             void* __restrict__ out0, void* __restrict__ out1, void* __restrict__ out2,
             int M, int N, int K) {
  __shared__ bf16 ldsA[128 * 32];
  __shared__ bf16 ldsB[128 * 32];
  const int tid = threadIdx.x;
  const int wid = tid >> 6, lane = tid & 63;
  const int lr = lane & 15, lg = lane >> 4;
  const int wr = wid >> 1, wc = wid & 1;
  const int m0 = blockIdx.y * 128, n0 = blockIdx.x * 128;

  const int rowA = tid >> 2;                    // 0..63 within a 64-row half
  const int cg = (tid & 3) ^ (rowA & 3);        // pre-swizzled global k-chunk
  const int slot = lg ^ (lane & 3);             // matching LDS read slot

  const f32x4 fzero = {0.f, 0.f, 0.f, 0.f};
  f32x4 acc[4][4];
#pragma unroll
  for (int m = 0; m < 4; m++)
#pragma unroll
    for (int n = 0; n < 4; n++) acc[m][n] = fzero;

  const int nk = K >> 5;
  for (int kt = 0; kt < nk; kt++) {
    const int kb = kt * 32 + cg * 8;
#pragma unroll
    for (int r = 0; r < 2; r++) {
      gload16(&A[(size_t)(m0 + r * 64 + rowA) * K + kb], &ldsA[r * 2048 + wid * 512]);
      gload16(&BT[(size_t)(n0 + r * 64 + rowA) * K + kb], &ldsB[r * 2048 + wid * 512]);
    }
    __syncthreads();
    bf16x8 af[4], bfr[4];
#pragma unroll
    for (int m = 0; m < 4; m++)
      af[m] = *reinterpret_cast<const bf16x8*>(&ldsA[(wr * 64 + m * 16 + lr) * 32 + slot * 8]);
#pragma unroll
    for (int n = 0; n < 4; n++)
      bfr[n] = *reinterpret_cast<const bf16x8*>(&ldsB[(wc * 64 + n * 16 + lr) * 32 + slot * 8]);
#pragma unroll
    for (int m = 0; m < 4; m++)
#pragma unroll
      for (int n = 0; n < 4; n++) acc[m][n] = mfma16(af[m], bfr[n], acc[m][n]);
    __syncthreads();
  }

#pragma unroll
  for (int m = 0; m < 4; m++)
#pragma unroll
    for (int n = 0; n < 4; n++)
#pragma unroll
      for (int i = 0; i < 4; i++) {
        int row = m0 + wr * 64 + m * 16 + 4 * lg + i;
        int col = n0 + wc * 64 + n * 16 + lr;
        float v = acc[m][n][i];
        int b = row >> 11, s = row & 2047;
        if (MODE == 1) {
          ((float*)out0)[(size_t)row * N + col] = v;
        } else if (MODE == 6) {
          if (col < 2048) {
            int h = col >> 7, d = col & 127;
            ((bf16*)out0)[((size_t)(b * 16 + h) * 2048 + s) * 192 + d] = (bf16)v;
          } else if (col < 3072) {
            ((bf16*)out1)[(size_t)row * 1024 + (col - 2048)] = (bf16)v;
          } else {
            ((bf16*)out2)[(size_t)row * 512 + (col - 3072)] = (bf16)v;
          }
        } else if (MODE == 7) {
          if (col < 512) {
            int kv = col >> 7, d = col & 127;
            ((bf16*)out0)[((size_t)(b * 4 + kv) * 2048 + s) * 192 + d] = (bf16)v;
          } else if (col < 1024) {
            int mm = col - 512, kv = mm >> 7, d = mm & 127;
            ((bf16*)out1)[((size_t)(b * 4 + kv) * 128 + d) * 2048 + s] = (bf16)v;
          } else {
            ((bf16*)out2)[(size_t)row * 256 + (col - 1024)] = (bf16)v;
          }
        }
      }
}

// ---------------- RoPE (position = head index, per reference quirk) ----------------
__global__ void rope_q_kernel(const bf16* __restrict__ raw, bf16* __restrict__ qbuf) {
  int idx = blockIdx.x * 256 + threadIdx.x;   // (rs,h,i): 4096*16*32
  int i = idx & 31;
  int h = (idx >> 5) & 15;
  int rs = idx >> 9;
  int b = rs >> 11, s = rs & 2047;
  float x1 = (float)raw[(size_t)rs * 1024 + h * 64 + 2 * i];
  float x2 = (float)raw[(size_t)rs * 1024 + h * 64 + 2 * i + 1];
  float freq = __expf(-(float)(2 * i) * (9.210340371976184f / 64.f)); // 10000^(-2i/64)
  float ang = (float)h * freq;
  float sn, cs;
  __sincosf(ang, &sn, &cs);
  size_t o = ((size_t)(b * 16 + h) * 2048 + s) * 192 + 128 + 2 * i;
  qbuf[o] = (bf16)(x1 * cs - x2 * sn);
  qbuf[o + 1] = (bf16)(x1 * sn + x2 * cs);
}

__global__ void rope_k_kernel(const bf16* __restrict__ raw, bf16* __restrict__ kbuf) {
  int idx = blockIdx.x * 256 + threadIdx.x;   // (rs,kv,i): 4096*4*32
  int i = idx & 31;
  int kv = (idx >> 5) & 3;
  int rs = idx >> 7;
  int b = rs >> 11, s = rs & 2047;
  float x1 = (float)raw[(size_t)rs * 256 + kv * 64 + 2 * i];
  float x2 = (float)raw[(size_t)rs * 256 + kv * 64 + 2 * i + 1];
  float freq = __expf(-(float)(2 * i) * (9.210340371976184f / 64.f));
  float ang = (float)kv * freq;
  float sn, cs;
  __sincosf(ang, &sn, &cs);
  size_t o = ((size_t)(b * 4 + kv) * 2048 + s) * 192 + 128 + 2 * i;
  kbuf[o] = (bf16)(x1 * cs - x2 * sn);
  kbuf[o + 1] = (bf16)(x1 * sn + x2 * cs);
}

// ---------------- flash attention (causal, GQA 4:1) ----------------
// grid (S/64, H, B); 4 waves x 16 q-rows; KV tile 64 staged in LDS via
// global_load_lds with both-sides XOR swizzle sigma(o) = o ^ (((o>>7)&7)<<4).
// K tile [64][192] bf16 = 24KB (contiguous in global); V^T tile [128][64] = 16KB.
// LDS total 49KB -> 3 blocks/CU.
__global__ __launch_bounds__(256, 3)
void attn_kernel(const bf16* __restrict__ qbuf, const bf16* __restrict__ kbuf,
                 const bf16* __restrict__ vt, bf16* __restrict__ obuf) {
  __shared__ __align__(16) char Klds[24576];
  __shared__ __align__(16) char Vlds[16384];
  __shared__ __align__(16) bf16 Plds[4][16][72];   // per-wave P tile, padded stride

  const int tid = threadIdx.x;
  const int wid = tid >> 6, lane = tid & 63;
  const int lr = lane & 15, lg = lane >> 4;
  const int bx = blockIdx.x, h = blockIdx.y, b = blockIdx.z;
  const int q0 = bx * 64, qrb = q0 + wid * 16;
  const bf16* Q = qbuf + (size_t)(b * 16 + h) * 2048 * 192;
  const char* Kg = (const char*)(kbuf + (size_t)(b * 4 + (h >> 2)) * 2048 * 192);
  const char* Vg = (const char*)(vt + (size_t)(b * 4 + (h >> 2)) * 128 * 2048);

  // per-lane staging source offsets (swizzled), loop-invariant
  int koff[6], voff[4];
#pragma unroll
  for (int c = 0; c < 6; c++) {
    int o = (wid * 6 + c) * 1024 + lane * 16;
    koff[c] = o ^ ((lane >> 3) << 4);          // K tile contiguous: sigma(o)
  }
#pragma unroll
  for (int c = 0; c < 4; c++) {
    int o = (wid * 4 + c) * 1024 + lane * 16;
    int d = o >> 7;                            // V^T row (d-dim)
    voff[c] = d * 4096 + (((lane & 7) * 16) ^ ((lane >> 3) << 4));
  }
  // read-side XOR values: K: ((3*lr + (kk>>1))&7)<<4 ; V: (lr&7)<<4
  const int xk0 = ((3 * lr + 0) & 7) << 4;
  const int xk1 = ((3 * lr + 1) & 7) << 4;
  const int xk2 = ((3 * lr + 2) & 7) << 4;
  const int xv  = (lr & 7) << 4;

  bf16x8 qf[6];
#pragma unroll
  for (int kk = 0; kk < 6; kk++)
    qf[kk] = *reinterpret_cast<const bf16x8*>(&Q[(size_t)(qrb + lr) * 192 + kk * 32 + lg * 8]);

  const f32x4 fzero = {0.f, 0.f, 0.f, 0.f};
  f32x4 acco[8];
#pragma unroll
  for (int nn = 0; nn < 8; nn++) acco[nn] = fzero;
  float mrow[4] = {-1e30f, -1e30f, -1e30f, -1e30f};
  float lsum[4] = {0.f, 0.f, 0.f, 0.f};
  const float scale = 0.07216878364870323f;  // 1/sqrt(192)

  for (int j = 0; j <= bx; j++) {
    // ---- stage K/V tile j into LDS (coalesced, swizzled source) ----
    const char* Kt = Kg + (size_t)j * 24576;   // contiguous 64x384B tile
    const char* Vtb = Vg + (size_t)j * 128;    // col offset (64 s * 2B)
#pragma unroll
    for (int c = 0; c < 6; c++)
      gload16(Kt + koff[c], Klds + (wid * 6 + c) * 1024);
#pragma unroll
    for (int c = 0; c < 4; c++)
      gload16(Vtb + voff[c], Vlds + (wid * 4 + c) * 1024);
    __syncthreads();

    // ---- QK^T from LDS ----
    const int k0 = j * 64;
    f32x4 sacc[4];
#pragma unroll
    for (int n = 0; n < 4; n++) sacc[n] = fzero;
    __builtin_amdgcn_s_setprio(1);
#pragma unroll
    for (int n = 0; n < 4; n++) {
      const int rb = (n * 16 + lr) * 384;
#pragma unroll
      for (int kk = 0; kk < 6; kk++) {
        const int x = (kk < 2) ? xk0 : ((kk < 4) ? xk1 : xk2);
        bf16x8 kf = *reinterpret_cast<const bf16x8*>(Klds + rb + ((kk * 64 + lg * 16) ^ x));
        sacc[n] = mfma16(qf[kk], kf, sacc[n]);
      }
    }
    __builtin_amdgcn_s_setprio(0);

    // ---- online softmax ----
    const bool diag = (j == bx);
#pragma unroll
    for (int i = 0; i < 4; i++) {
      const int row = qrb + 4 * lg + i;
      float s[4];
#pragma unroll
      for (int n = 0; n < 4; n++) s[n] = sacc[n][i] * scale;
      if (diag) {
#pragma unroll
        for (int n = 0; n < 4; n++)
          if (k0 + n * 16 + lr > row) s[n] = -1e30f;
      }
      float mx = fmaxf(fmaxf(s[0], s[1]), fmaxf(s[2], s[3]));
#pragma unroll
      for (int off = 1; off < 16; off <<= 1) mx = fmaxf(mx, __shfl_xor(mx, off, 16));
      float mnew = fmaxf(mrow[i], mx);
      float fs = __expf(mrow[i] - mnew);
      float p[4], sum = 0.f;
#pragma unroll
      for (int n = 0; n < 4; n++) { p[n] = __expf(s[n] - mnew); sum += p[n]; }
#pragma unroll
      for (int off = 1; off < 16; off <<= 1) sum += __shfl_xor(sum, off, 16);
      mrow[i] = mnew;
      lsum[i] = lsum[i] * fs + sum;
#pragma unroll
      for (int n = 0; n < 4; n++) Plds[wid][4 * lg + i][n * 16 + lr] = (bf16)p[n];
#pragma unroll
      for (int nn = 0; nn < 8; nn++) acco[nn][i] *= fs;
    }

    // ---- PV from LDS ----
    __builtin_amdgcn_s_setprio(1);
#pragma unroll
    for (int ks = 0; ks < 2; ks++) {
      bf16x8 pf = *reinterpret_cast<const bf16x8*>(&Plds[wid][lr][ks * 32 + lg * 8]);
#pragma unroll
      for (int nn = 0; nn < 8; nn++) {
        bf16x8 vf = *reinterpret_cast<const bf16x8*>(
            Vlds + (nn * 16 + lr) * 128 + ((ks * 64 + lg * 16) ^ xv));
        acco[nn] = mfma16(pf, vf, acco[nn]);
      }
    }
    __builtin_amdgcn_s_setprio(0);
    __syncthreads();   // protect K/V LDS from next stage
  }

#pragma unroll
  for (int nn = 0; nn < 8; nn++)
#pragma unroll
    for (int i = 0; i < 4; i++) {
      int row = qrb + 4 * lg + i;
      float o = acco[nn][i] / lsum[i];
      obuf[(size_t)(b * 2048 + row) * 2048 + h * 128 + nn * 16 + lr] = (bf16)o;
    }
}

// ---------------- launcher ----------------
extern "C" void kernel_launch(void* const* d_in, const int* in_sizes, int n_in,
                              void* d_out, int out_size, void* d_ws, size_t ws_size,
                              hipStream_t stream) {
  (void)in_sizes; (void)n_in; (void)out_size; (void)ws_size;
  const float* Xf     = (const float*)d_in[0];
  const float* Wq     = (const float*)d_in[1];
  const float* Wkvc   = (const float*)d_in[2];
  const float* Wkdec  = (const float*)d_in[3];
  const float* Wvdec  = (const float*)d_in[4];
  const float* Wqrope = (const float*)d_in[5];
  const float* Wkrope = (const float*)d_in[6];
  const float* Wo     = (const float*)d_in[7];
  float* Out = (float*)d_out;
  char* ws = (char*)d_ws;

  bf16* Xb     = (bf16*)(ws + OFF_XB);
  bf16* WqT    = (bf16*)(ws + OFF_WQT);
  bf16* WqrT   = (bf16*)(ws + OFF_WQRT);
  bf16* WkvcT  = (bf16*)(ws + OFF_WKVCT);
  bf16* WkdT   = (bf16*)(ws + OFF_WKDT);
  bf16* WvdT   = (bf16*)(ws + OFF_WVDT);
  bf16* WkrT   = (bf16*)(ws + OFF_WKRT);
  bf16* WoT    = (bf16*)(ws + OFF_WOT);
  bf16* Cb     = (bf16*)(ws + OFF_CB);
  bf16* Qbuf   = (bf16*)(ws + OFF_QBUF);
  bf16* Kbuf   = (bf16*)(ws + OFF_KBUF);
  bf16* Vt     = (bf16*)(ws + OFF_VT);
  bf16* Qrr    = (bf16*)(ws + OFF_QRR);
  bf16* Krr    = (bf16*)(ws + OFF_KRR);
  bf16* Obuf   = (bf16*)(ws + OFF_OBUF);

  cast_x_kernel<<<2048, 256, 0, stream>>>(Xf, Xb, (4096 * 2048) / 4);

  // fused transpose-cast of all 7 weights
  TDescs D;
  const float* ins[7] = {Wq, Wqrope, Wkvc, Wkdec, Wvdec, Wkrope, Wo};
  bf16* outs[7] = {WqT, WqrT, WkvcT, WkdT, WvdT, WkrT, WoT};
  int kds[7] = {2048, 2048, 2048, 512, 512, 512, 2048};
  int nds[7] = {2048, 1024, 512, 512, 512, 256, 2048};
  int gts[7] = {0, 0, 0, 0, 0, 0, 1};
  int acc_t = 0;
  for (int m = 0; m < 7; m++) {
    D.in[m] = ins[m]; D.out[m] = outs[m];
    D.Kd[m] = kds[m]; D.Nd[m] = nds[m]; D.gather[m] = gts[m];
    D.tile0[m] = acc_t;
    acc_t += (nds[m] / 32) * (kds[m] / 32);
  }
  D.tile0[7] = acc_t;   // 11904
  transpose_cast_fused<<<acc_t, dim3(32, 8), 0, stream>>>(D);

  // mega-GEMM 1: X @ [WqT | WqropeT | WkvcT]^T  -> Qbuf scatter, Qrr, Cb
  gemm_bt<6><<<dim3(28, 32), 256, 0, stream>>>(Xb, WqT, Qbuf, Qrr, Cb, 4096, 3584, 2048);
  // mega-GEMM 2: Cb @ [WkdecT | WvdecT | WkropeT]^T -> Kbuf scatter, Vt scatter, Krr
  gemm_bt<7><<<dim3(10, 32), 256, 0, stream>>>(Cb, WkdT, Kbuf, Vt, Krr, 4096, 1280, 512);

  rope_q_kernel<<<8192, 256, 0, stream>>>(Qrr, Qbuf);
  rope_k_kernel<<<2048, 256, 0, stream>>>(Krr, Kbuf);

  attn_kernel<<<dim3(32, 16, 2), 256, 0, stream>>>(Qbuf, Kbuf, Vt, Obuf);

  gemm_bt<1><<<dim3(16, 32), 256, 0, stream>>>(Obuf, WoT, Out, nullptr, nullptr, 4096, 2048, 2048);
}

// Round 4
// 377.948 us; speedup vs baseline: 2.4509x; 1.2606x over previous
//
#include <hip/hip_runtime.h>
#include <hip/hip_bf16.h>
#include <stdint.h>

// MLA attention, bf16 MFMA pipeline.
// B=2 S=2048 HID=2048 H=16 KV=4 HD=128 RD=64 FULL=192
// RoPE quirk: reference indexes cos/sin by HEAD index (x.shape[-2]), not position.
// Scale 1/sqrt(192) is folded into Q (GEMM epilogue + rope_q).

typedef __bf16 bf16;
typedef __bf16 bf16x8 __attribute__((ext_vector_type(8)));
typedef __bf16 bf16x4 __attribute__((ext_vector_type(4)));
typedef float f32x4 __attribute__((ext_vector_type(4)));

#define GAS __attribute__((address_space(1)))
#define LAS __attribute__((address_space(3)))

__device__ __forceinline__ void gload16(const void* g, void* l) {
  __builtin_amdgcn_global_load_lds((GAS void*)(g), (LAS void*)(l), 16, 0, 0);
}

__device__ __forceinline__ f32x4 mfma16(bf16x8 a, bf16x8 b, f32x4 c) {
  return __builtin_amdgcn_mfma_f32_16x16x32_bf16(a, b, c, 0, 0, 0);
}

// DPP lane-rotate within 16-lane rows (VALU pipe, not DS)
template<int CTRL>
__device__ __forceinline__ float dppmov(float x) {
  int v = __builtin_amdgcn_update_dpp(0, __float_as_int(x), CTRL, 0xF, 0xF, false);
  return __int_as_float(v);
}
__device__ __forceinline__ float rowmax16(float x) {
  x = fmaxf(x, dppmov<0x128>(x));  // row_ror:8
  x = fmaxf(x, dppmov<0x124>(x));  // row_ror:4
  x = fmaxf(x, dppmov<0x122>(x));  // row_ror:2
  x = fmaxf(x, dppmov<0x121>(x));  // row_ror:1
  return x;
}
__device__ __forceinline__ float rowsum16(float x) {
  x += dppmov<0x128>(x);
  x += dppmov<0x124>(x);
  x += dppmov<0x122>(x);
  x += dppmov<0x121>(x);
  return x;
}

template<bool V> struct BoolC { static constexpr bool v = V; };

// ---------------- workspace layout (bytes) ----------------
#define OFF_XB    0ull                         // X bf16       4096x2048
#define OFF_WQT   (OFF_XB    + 16777216ull)    // WqT          2048x2048
#define OFF_WQRT  (OFF_WQT   + 8388608ull)     // WqropeT      1024x2048
#define OFF_WKVCT (OFF_WQRT  + 4194304ull)     // WkvcT        512x2048
#define OFF_WKDT  (OFF_WKVCT + 2097152ull)     // WkdecT       512x512
#define OFF_WVDT  (OFF_WKDT  + 524288ull)      // WvdecT       512x512
#define OFF_WKRT  (OFF_WVDT  + 524288ull)      // WkropeT      256x512
#define OFF_WOT   (OFF_WKRT  + 262144ull)      // WoT(gather)  2048x2048
#define OFF_CB    (OFF_WOT   + 8388608ull)     // c bf16       4096x512
#define OFF_QBUF  (OFF_CB    + 4194304ull)     // q (b,h,s,192), pre-scaled
#define OFF_KBUF  (OFF_QBUF  + 25165824ull)    // k (b,kv,s,192)
#define OFF_VT    (OFF_KBUF  + 6291456ull)     // vT (b,kv,128,s)
#define OFF_QRR   (OFF_VT    + 4194304ull)     // q-rope raw   4096x1024
#define OFF_KRR   (OFF_QRR   + 8388608ull)     // k-rope raw   4096x256
#define OFF_OBUF  (OFF_KRR   + 2097152ull)     // attn out     4096x2048

#define QSCALE 0.07216878364870323f            // 1/sqrt(192)

// ---------------- cast f32 -> bf16 ----------------
__global__ void cast_x_kernel(const float* __restrict__ in, bf16* __restrict__ out, int n4) {
  int i = blockIdx.x * blockDim.x + threadIdx.x;
  int stride = gridDim.x * blockDim.x;
  for (; i < n4; i += stride) {
    float4 v = reinterpret_cast<const float4*>(in)[i];
    bf16x4 o;
    o[0] = (bf16)v.x; o[1] = (bf16)v.y; o[2] = (bf16)v.z; o[3] = (bf16)v.w;
    reinterpret_cast<bf16x4*>(out)[i] = o;
  }
}

// ---------------- fused transpose-cast: 7 matrices, one launch ----------------
struct TDescs {
  const float* in[7];
  bf16* out[7];
  int Kd[7], Nd[7], gather[7];
  int tile0[8];
};

__global__ void transpose_cast_fused(TDescs D) {
  __shared__ float t[32][33];
  int bid = blockIdx.x;
  int m = 0;
  while (bid >= D.tile0[m + 1]) m++;        // uniform per block
  int local = bid - D.tile0[m];
  const float* in = D.in[m];
  bf16* out = D.out[m];
  int Kd = D.Kd[m], Nd = D.Nd[m], gather = D.gather[m];
  int txn = Nd >> 5;
  int n0 = (local % txn) * 32, k0 = (local / txn) * 32;
  int tx = threadIdx.x, ty = threadIdx.y;
#pragma unroll
  for (int i = 0; i < 4; i++) {
    int k = k0 + ty + i * 8;
    int kr = gather ? ((k >> 7) * 192 + (k & 127)) : k;
    t[ty + i * 8][tx] = in[(size_t)kr * Nd + n0 + tx];
  }
  __syncthreads();
#pragma unroll
  for (int i = 0; i < 4; i++) {
    int n = n0 + ty + i * 8;
    out[(size_t)n * Kd + k0 + tx] = (bf16)t[tx][ty + i * 8];
  }
}

// ---------------- GEMM: C(MxN) = A(MxK,bf16,rowmaj) @ BT(NxK,bf16,rowmaj)^T ----------------
// MODE 1: f32 plain rowmajor (out0)
// MODE 6: mega1 routing: col<2048 -> Qbuf scatter *QSCALE, col<3072 -> Qrr, else Cb
// MODE 7: mega2 routing: col<512 -> Kbuf scatter, col<1024 -> Vt transpose scatter, else Krr
template<int MODE>
__global__ __launch_bounds__(256, 2)
void gemm_bt(const bf16* __restrict__ A, const bf16* __restrict__ BT,
             void* __restrict__ out0, void* __restrict__ out1, void* __restrict__ out2,
             int M, int N, int K) {
  __shared__ bf16 ldsA[128 * 32];
  __shared__ bf16 ldsB[128 * 32];
  const int tid = threadIdx.x;
  const int wid = tid >> 6, lane = tid & 63;
  const int lr = lane & 15, lg = lane >> 4;
  const int wr = wid >> 1, wc = wid & 1;
  const int m0 = blockIdx.y * 128, n0 = blockIdx.x * 128;

  const int rowA = tid >> 2;                    // 0..63 within a 64-row half
  const int cg = (tid & 3) ^ (rowA & 3);        // pre-swizzled global k-chunk
  const int slot = lg ^ (lane & 3);             // matching LDS read slot

  const f32x4 fzero = {0.f, 0.f, 0.f, 0.f};
  f32x4 acc[4][4];
#pragma unroll
  for (int m = 0; m < 4; m++)
#pragma unroll
    for (int n = 0; n < 4; n++) acc[m][n] = fzero;

  const int nk = K >> 5;
  for (int kt = 0; kt < nk; kt++) {
    const int kb = kt * 32 + cg * 8;
#pragma unroll
    for (int r = 0; r < 2; r++) {
      gload16(&A[(size_t)(m0 + r * 64 + rowA) * K + kb], &ldsA[r * 2048 + wid * 512]);
      gload16(&BT[(size_t)(n0 + r * 64 + rowA) * K + kb], &ldsB[r * 2048 + wid * 512]);
    }
    __syncthreads();
    bf16x8 af[4], bfr[4];
#pragma unroll
    for (int m = 0; m < 4; m++)
      af[m] = *reinterpret_cast<const bf16x8*>(&ldsA[(wr * 64 + m * 16 + lr) * 32 + slot * 8]);
#pragma unroll
    for (int n = 0; n < 4; n++)
      bfr[n] = *reinterpret_cast<const bf16x8*>(&ldsB[(wc * 64 + n * 16 + lr) * 32 + slot * 8]);
#pragma unroll
    for (int m = 0; m < 4; m++)
#pragma unroll
      for (int n = 0; n < 4; n++) acc[m][n] = mfma16(af[m], bfr[n], acc[m][n]);
    __syncthreads();
  }

#pragma unroll
  for (int m = 0; m < 4; m++)
#pragma unroll
    for (int n = 0; n < 4; n++)
#pragma unroll
      for (int i = 0; i < 4; i++) {
        int row = m0 + wr * 64 + m * 16 + 4 * lg + i;
        int col = n0 + wc * 64 + n * 16 + lr;
        float v = acc[m][n][i];
        int b = row >> 11, s = row & 2047;
        if (MODE == 1) {
          ((float*)out0)[(size_t)row * N + col] = v;
        } else if (MODE == 6) {
          if (col < 2048) {
            int h = col >> 7, d = col & 127;
            ((bf16*)out0)[((size_t)(b * 16 + h) * 2048 + s) * 192 + d] = (bf16)(v * QSCALE);
          } else if (col < 3072) {
            ((bf16*)out1)[(size_t)row * 1024 + (col - 2048)] = (bf16)v;
          } else {
            ((bf16*)out2)[(size_t)row * 512 + (col - 3072)] = (bf16)v;
          }
        } else if (MODE == 7) {
          if (col < 512) {
            int kv = col >> 7, d = col & 127;
            ((bf16*)out0)[((size_t)(b * 4 + kv) * 2048 + s) * 192 + d] = (bf16)v;
          } else if (col < 1024) {
            int mm = col - 512, kv = mm >> 7, d = mm & 127;
            ((bf16*)out1)[((size_t)(b * 4 + kv) * 128 + d) * 2048 + s] = (bf16)v;
          } else {
            ((bf16*)out2)[(size_t)row * 256 + (col - 1024)] = (bf16)v;
          }
        }
      }
}

// ---------------- RoPE (position = head index, per reference quirk) ----------------
__global__ void rope_q_kernel(const bf16* __restrict__ raw, bf16* __restrict__ qbuf) {
  int idx = blockIdx.x * 256 + threadIdx.x;   // (rs,h,i): 4096*16*32
  int i = idx & 31;
  int h = (idx >> 5) & 15;
  int rs = idx >> 9;
  int b = rs >> 11, s = rs & 2047;
  float x1 = (float)raw[(size_t)rs * 1024 + h * 64 + 2 * i];
  float x2 = (float)raw[(size_t)rs * 1024 + h * 64 + 2 * i + 1];
  float freq = __expf(-(float)(2 * i) * (9.210340371976184f / 64.f)); // 10000^(-2i/64)
  float ang = (float)h * freq;
  float sn, cs;
  __sincosf(ang, &sn, &cs);
  size_t o = ((size_t)(b * 16 + h) * 2048 + s) * 192 + 128 + 2 * i;
  qbuf[o] = (bf16)((x1 * cs - x2 * sn) * QSCALE);
  qbuf[o + 1] = (bf16)((x1 * sn + x2 * cs) * QSCALE);
}

__global__ void rope_k_kernel(const bf16* __restrict__ raw, bf16* __restrict__ kbuf) {
  int idx = blockIdx.x * 256 + threadIdx.x;   // (rs,kv,i): 4096*4*32
  int i = idx & 31;
  int kv = (idx >> 5) & 3;
  int rs = idx >> 7;
  int b = rs >> 11, s = rs & 2047;
  float x1 = (float)raw[(size_t)rs * 256 + kv * 64 + 2 * i];
  float x2 = (float)raw[(size_t)rs * 256 + kv * 64 + 2 * i + 1];
  float freq = __expf(-(float)(2 * i) * (9.210340371976184f / 64.f));
  float ang = (float)kv * freq;
  float sn, cs;
  __sincosf(ang, &sn, &cs);
  size_t o = ((size_t)(b * 4 + kv) * 2048 + s) * 192 + 128 + 2 * i;
  kbuf[o] = (bf16)(x1 * cs - x2 * sn);
  kbuf[o + 1] = (bf16)(x1 * sn + x2 * cs);
}

// ---------------- flash attention (causal, GQA 4:1), paired q-tiles ----------------
// grid (16, H, B); block px handles q-tiles A=px and B=31-px (uniform ~33 tiles).
// K/V staged once per tile, shared by both q-tiles (2x MFMA per DS read).
// LDS: K 24KB + V 16KB + 2x P 9KB = 58KB -> 2 blocks/CU; 512 blocks total.
__global__ __launch_bounds__(256, 2)
void attn_kernel(const bf16* __restrict__ qbuf, const bf16* __restrict__ kbuf,
                 const bf16* __restrict__ vt, bf16* __restrict__ obuf) {
  __shared__ __align__(16) char Klds[24576];
  __shared__ __align__(16) char Vlds[16384];
  __shared__ __align__(16) bf16 PldsA[4][16][72];
  __shared__ __align__(16) bf16 PldsB[4][16][72];

  const int tid = threadIdx.x;
  const int wid = tid >> 6, lane = tid & 63;
  const int lr = lane & 15, lg = lane >> 4;
  const int px = blockIdx.x, h = blockIdx.y, b = blockIdx.z;
  const int bxB = 31 - px;
  const int qrbA = px * 64 + wid * 16, qrbB = bxB * 64 + wid * 16;
  const bf16* Q = qbuf + (size_t)(b * 16 + h) * 2048 * 192;
  const char* Kg = (const char*)(kbuf + (size_t)(b * 4 + (h >> 2)) * 2048 * 192);
  const char* Vg = (const char*)(vt + (size_t)(b * 4 + (h >> 2)) * 128 * 2048);

  // per-lane staging source offsets (swizzled), loop-invariant
  int koff[6], voff[4];
#pragma unroll
  for (int c = 0; c < 6; c++) {
    int o = (wid * 6 + c) * 1024 + lane * 16;
    koff[c] = o ^ ((lane >> 3) << 4);          // K tile contiguous: sigma(o)
  }
#pragma unroll
  for (int c = 0; c < 4; c++) {
    int o = (wid * 4 + c) * 1024 + lane * 16;
    int d = o >> 7;                            // V^T row (d-dim)
    voff[c] = d * 4096 + (((lane & 7) * 16) ^ ((lane >> 3) << 4));
  }
  const int xk0 = ((3 * lr + 0) & 7) << 4;
  const int xk1 = ((3 * lr + 1) & 7) << 4;
  const int xk2 = ((3 * lr + 2) & 7) << 4;
  const int xv  = (lr & 7) << 4;

  bf16x8 qfA[6], qfB[6];
#pragma unroll
  for (int kk = 0; kk < 6; kk++) {
    qfA[kk] = *reinterpret_cast<const bf16x8*>(&Q[(size_t)(qrbA + lr) * 192 + kk * 32 + lg * 8]);
    qfB[kk] = *reinterpret_cast<const bf16x8*>(&Q[(size_t)(qrbB + lr) * 192 + kk * 32 + lg * 8]);
  }

  const f32x4 fzero = {0.f, 0.f, 0.f, 0.f};
  f32x4 accA[8], accB[8];
#pragma unroll
  for (int nn = 0; nn < 8; nn++) { accA[nn] = fzero; accB[nn] = fzero; }
  float mA[4] = {-1e30f, -1e30f, -1e30f, -1e30f};
  float mB[4] = {-1e30f, -1e30f, -1e30f, -1e30f};
  float lA[4] = {0.f, 0.f, 0.f, 0.f};
  float lB[4] = {0.f, 0.f, 0.f, 0.f};

  // online softmax for one q-tile; sacc pre-scaled (scale folded into Q)
  auto softmax = [&](f32x4* sacc, float* mrow, float* lsum, f32x4* acco,
                     bf16 (*P)[72], int diag, int qrb, int k0) {
    float fsv[4];
    int grow = 0;
#pragma unroll
    for (int i = 0; i < 4; i++) {
      const int row = qrb + 4 * lg + i;
      float s[4];
#pragma unroll
      for (int n = 0; n < 4; n++) s[n] = sacc[n][i];
      if (diag) {
#pragma unroll
        for (int n = 0; n < 4; n++)
          if (k0 + n * 16 + lr > row) s[n] = -1e30f;
      }
      float mx = rowmax16(fmaxf(fmaxf(s[0], s[1]), fmaxf(s[2], s[3])));
      int g = mx > mrow[i] + 8.f;
      float mnew = g ? mx : mrow[i];
      float fs = g ? __expf(mrow[i] - mx) : 1.f;
      grow |= g;
      fsv[i] = fs;
      float p[4], sum = 0.f;
#pragma unroll
      for (int n = 0; n < 4; n++) { p[n] = __expf(s[n] - mnew); sum += p[n]; }
      sum = rowsum16(sum);
      mrow[i] = mnew;
      lsum[i] = lsum[i] * fs + sum;
#pragma unroll
      for (int n = 0; n < 4; n++) P[4 * lg + i][n * 16 + lr] = (bf16)p[n];
    }
    if (__any(grow)) {
#pragma unroll
      for (int nn = 0; nn < 8; nn++)
#pragma unroll
        for (int i = 0; i < 4; i++) acco[nn][i] *= fsv[i];
    }
  };

  auto tile_body = [&](auto DC, int j, int diagA, int diagB) {
    constexpr bool DUAL = decltype(DC)::v;
    // ---- stage K/V tile j into LDS (coalesced, swizzled source) ----
    const char* Kt = Kg + (size_t)j * 24576;
    const char* Vtb = Vg + (size_t)j * 128;
#pragma unroll
    for (int c = 0; c < 6; c++)
      gload16(Kt + koff[c], Klds + (wid * 6 + c) * 1024);
#pragma unroll
    for (int c = 0; c < 4; c++)
      gload16(Vtb + voff[c], Vlds + (wid * 4 + c) * 1024);
    __syncthreads();

    const int k0 = j * 64;
    f32x4 sA[4], sB[4];
#pragma unroll
    for (int n = 0; n < 4; n++) { sA[n] = fzero; sB[n] = fzero; }
    __builtin_amdgcn_s_setprio(1);
#pragma unroll
    for (int n = 0; n < 4; n++) {
      const int rb = (n * 16 + lr) * 384;
#pragma unroll
      for (int kk = 0; kk < 6; kk++) {
        const int x = (kk < 2) ? xk0 : ((kk < 4) ? xk1 : xk2);
        bf16x8 kf = *reinterpret_cast<const bf16x8*>(Klds + rb + ((kk * 64 + lg * 16) ^ x));
        sB[n] = mfma16(qfB[kk], kf, sB[n]);
        if constexpr (DUAL) sA[n] = mfma16(qfA[kk], kf, sA[n]);
      }
    }
    __builtin_amdgcn_s_setprio(0);

    softmax(sB, mB, lB, accB, PldsB[wid], diagB, qrbB, k0);
    if constexpr (DUAL) softmax(sA, mA, lA, accA, PldsA[wid], diagA, qrbA, k0);

    __builtin_amdgcn_s_setprio(1);
#pragma unroll
    for (int ks = 0; ks < 2; ks++) {
      bf16x8 pfB = *reinterpret_cast<const bf16x8*>(&PldsB[wid][lr][ks * 32 + lg * 8]);
      bf16x8 pfA;
      if constexpr (DUAL)
        pfA = *reinterpret_cast<const bf16x8*>(&PldsA[wid][lr][ks * 32 + lg * 8]);
#pragma unroll
      for (int nn = 0; nn < 8; nn++) {
        bf16x8 vf = *reinterpret_cast<const bf16x8*>(
            Vlds + (nn * 16 + lr) * 128 + ((ks * 64 + lg * 16) ^ xv));
        accB[nn] = mfma16(pfB, vf, accB[nn]);
        if constexpr (DUAL) accA[nn] = mfma16(pfA, vf, accA[nn]);
      }
    }
    __builtin_amdgcn_s_setprio(0);
    __syncthreads();
  };

  // phase 1: tiles shared by A and B; phase 2: B only (incl. B diagonal)
  for (int j = 0; j <= px; j++) tile_body(BoolC<true>{}, j, j == px, 0);
  for (int j = px + 1; j <= bxB; j++) tile_body(BoolC<false>{}, j, 0, j == bxB);

#pragma unroll
  for (int i = 0; i < 4; i++) { lA[i] = 1.f / lA[i]; lB[i] = 1.f / lB[i]; }
#pragma unroll
  for (int nn = 0; nn < 8; nn++)
#pragma unroll
    for (int i = 0; i < 4; i++) {
      int rowA = qrbA + 4 * lg + i, rowB = qrbB + 4 * lg + i;
      obuf[(size_t)(b * 2048 + rowA) * 2048 + h * 128 + nn * 16 + lr] = (bf16)(accA[nn][i] * lA[i]);
      obuf[(size_t)(b * 2048 + rowB) * 2048 + h * 128 + nn * 16 + lr] = (bf16)(accB[nn][i] * lB[i]);
    }
}

// ---------------- launcher ----------------
extern "C" void kernel_launch(void* const* d_in, const int* in_sizes, int n_in,
                              void* d_out, int out_size, void* d_ws, size_t ws_size,
                              hipStream_t stream) {
  (void)in_sizes; (void)n_in; (void)out_size; (void)ws_size;
  const float* Xf     = (const float*)d_in[0];
  const float* Wq     = (const float*)d_in[1];
  const float* Wkvc   = (const float*)d_in[2];
  const float* Wkdec  = (const float*)d_in[3];
  const float* Wvdec  = (const float*)d_in[4];
  const float* Wqrope = (const float*)d_in[5];
  const float* Wkrope = (const float*)d_in[6];
  const float* Wo     = (const float*)d_in[7];
  float* Out = (float*)d_out;
  char* ws = (char*)d_ws;

  bf16* Xb     = (bf16*)(ws + OFF_XB);
  bf16* WqT    = (bf16*)(ws + OFF_WQT);
  bf16* WqrT   = (bf16*)(ws + OFF_WQRT);
  bf16* WkvcT  = (bf16*)(ws + OFF_WKVCT);
  bf16* WkdT   = (bf16*)(ws + OFF_WKDT);
  bf16* WvdT   = (bf16*)(ws + OFF_WVDT);
  bf16* WkrT   = (bf16*)(ws + OFF_WKRT);
  bf16* WoT    = (bf16*)(ws + OFF_WOT);
  bf16* Cb     = (bf16*)(ws + OFF_CB);
  bf16* Qbuf   = (bf16*)(ws + OFF_QBUF);
  bf16* Kbuf   = (bf16*)(ws + OFF_KBUF);
  bf16* Vt     = (bf16*)(ws + OFF_VT);
  bf16* Qrr    = (bf16*)(ws + OFF_QRR);
  bf16* Krr    = (bf16*)(ws + OFF_KRR);
  bf16* Obuf   = (bf16*)(ws + OFF_OBUF);

  cast_x_kernel<<<2048, 256, 0, stream>>>(Xf, Xb, (4096 * 2048) / 4);

  TDescs D;
  const float* ins[7] = {Wq, Wqrope, Wkvc, Wkdec, Wvdec, Wkrope, Wo};
  bf16* outs[7] = {WqT, WqrT, WkvcT, WkdT, WvdT, WkrT, WoT};
  int kds[7] = {2048, 2048, 2048, 512, 512, 512, 2048};
  int nds[7] = {2048, 1024, 512, 512, 512, 256, 2048};
  int gts[7] = {0, 0, 0, 0, 0, 0, 1};
  int acc_t = 0;
  for (int m = 0; m < 7; m++) {
    D.in[m] = ins[m]; D.out[m] = outs[m];
    D.Kd[m] = kds[m]; D.Nd[m] = nds[m]; D.gather[m] = gts[m];
    D.tile0[m] = acc_t;
    acc_t += (nds[m] / 32) * (kds[m] / 32);
  }
  D.tile0[7] = acc_t;   // 11904
  transpose_cast_fused<<<acc_t, dim3(32, 8), 0, stream>>>(D);

  // mega-GEMM 1: X @ [WqT | WqropeT | WkvcT]^T  -> Qbuf scatter (scaled), Qrr, Cb
  gemm_bt<6><<<dim3(28, 32), 256, 0, stream>>>(Xb, WqT, Qbuf, Qrr, Cb, 4096, 3584, 2048);
  // mega-GEMM 2: Cb @ [WkdecT | WvdecT | WkropeT]^T -> Kbuf scatter, Vt scatter, Krr
  gemm_bt<7><<<dim3(10, 32), 256, 0, stream>>>(Cb, WkdT, Kbuf, Vt, Krr, 4096, 1280, 512);

  rope_q_kernel<<<8192, 256, 0, stream>>>(Qrr, Qbuf);
  rope_k_kernel<<<2048, 256, 0, stream>>>(Krr, Kbuf);

  attn_kernel<<<dim3(16, 16, 2), 256, 0, stream>>>(Qbuf, Kbuf, Vt, Obuf);

  gemm_bt<1><<<dim3(16, 32), 256, 0, stream>>>(Obuf, WoT, Out, nullptr, nullptr, 4096, 2048, 2048);
}